// Round 7
// baseline (259.030 us; speedup 1.0000x reference)
//
#include <hip/hip_runtime.h>
#include <hip/hip_fp16.h>

// Ontomap: loss = sum((n2f@n_e - f_e)^2) + sum((m2f@m_e - f_e)^2)
// B = 1,048,576, D = 64.
// Round 17: per-wave MLP via gather double-buffering. R16 (prologue hoist)
// hit 53us/2.98TB/s; occupancy 31% is below the 50% launch-bounds cap, so
// the limiter is in-flight misses per wave, not wave count. Unroll the
// sample loop by 2 with two named gather-register sets (A/B, 6 ulonglong2
// each): issue set k+1's 6 gathers before computing set k. VGPR ~110 < 128
// cap of (256,4) -- no spill expected (R9's spill was from buffering
// unpacked fragments, not 96B of raw gather bytes). Numerics unchanged.

typedef _Float16 half8 __attribute__((ext_vector_type(8)));
typedef __fp16  fp16x2 __attribute__((ext_vector_type(2)));
typedef float floatx16 __attribute__((ext_vector_type(16)));

#define NBLOCKS 2048
#define SPB 128                 // samples per block-iteration: 4 waves * 32
#define NCI_ELEMS 9600000       // 150000 * 64
#define FMA_ELEMS 6400000       // 100000 * 64
#define FRAG_LONGS 512          // 2 matrices * 8 frags * 64 lanes

__device__ inline half8 cvt8(float4 a, float4 b) {
    union { half8 h; fp16x2 h2[4]; } u;
    u.h2[0] = __builtin_amdgcn_cvt_pkrtz(a.x, a.y);
    u.h2[1] = __builtin_amdgcn_cvt_pkrtz(a.z, a.w);
    u.h2[2] = __builtin_amdgcn_cvt_pkrtz(b.x, b.y);
    u.h2[3] = __builtin_amdgcn_cvt_pkrtz(b.z, b.w);
    return u.h;
}

__device__ inline uint2 pack4(float4 v) {
    union { fp16x2 h2[2]; uint2 u; } p;
    p.h2[0] = __builtin_amdgcn_cvt_pkrtz(v.x, v.y);
    p.h2[1] = __builtin_amdgcn_cvt_pkrtz(v.z, v.w);
    return p.u;
}

// 8 fp32 -> 8 fp8-e4m3 bytes (ascending order).
__device__ inline uint2 pack8_fp8(float4 a, float4 b) {
    int lo = 0, hi = 0;
    lo = __builtin_amdgcn_cvt_pk_fp8_f32(a.x, a.y, lo, false);
    lo = __builtin_amdgcn_cvt_pk_fp8_f32(a.z, a.w, lo, true);
    hi = __builtin_amdgcn_cvt_pk_fp8_f32(b.x, b.y, hi, false);
    hi = __builtin_amdgcn_cvt_pk_fp8_f32(b.z, b.w, hi, true);
    uint2 r; r.x = (unsigned)lo; r.y = (unsigned)hi; return r;
}

__device__ inline long pack8_fp8_l(const float* p) {
    uint2 b = pack8_fp8(*(const float4*)p, *(const float4*)(p + 4));
    return (long)(((unsigned long)b.y << 32) | b.x);
}

// ---- streaming conversion: both tables -> fp8, into workspace.
// Also zeroes the loss accumulator and precomputes the per-lane packed
// B-fragments for both matrices (frag[(nt*4+t)*64 + lane], 8KB total).
__global__ __launch_bounds__(256) void convert_kernel(
    const float4* __restrict__ nci, const float4* __restrict__ fma,
    uint4* __restrict__ nci8, uint4* __restrict__ fma8, float* __restrict__ out,
    const float* __restrict__ n2f, const float* __restrict__ m2f,
    long* __restrict__ fragN, long* __restrict__ fragM)
{
    const int stride = gridDim.x * blockDim.x;
    const int tid = blockIdx.x * blockDim.x + threadIdx.x;
    if (tid == 0) out[0] = 0.0f;
    if (blockIdx.x == 0 && threadIdx.x < 64) {
        const int lane = threadIdx.x;
        const int l31 = lane & 31;
        const int hoff = (lane >> 5) * 32;
#pragma unroll
        for (int nt = 0; nt < 2; ++nt) {
#pragma unroll
            for (int t = 0; t < 4; ++t) {
                fragN[(nt * 4 + t) * 64 + lane] =
                    pack8_fp8_l(n2f + (nt * 32 + l31) * 64 + hoff + t * 8);
                fragM[(nt * 4 + t) * 64 + lane] =
                    pack8_fp8_l(m2f + (nt * 32 + l31) * 64 + hoff + t * 8);
            }
        }
    }
    for (int i = tid; i < NCI_ELEMS / 16; i += stride) {
        uint2 lo = pack8_fp8(nci[4 * i],     nci[4 * i + 1]);
        uint2 hi = pack8_fp8(nci[4 * i + 2], nci[4 * i + 3]);
        nci8[i] = make_uint4(lo.x, lo.y, hi.x, hi.y);
    }
    for (int i = tid; i < FMA_ELEMS / 16; i += stride) {
        uint2 lo = pack8_fp8(fma[4 * i],     fma[4 * i + 1]);
        uint2 hi = pack8_fp8(fma[4 * i + 2], fma[4 * i + 3]);
        fma8[i] = make_uint4(lo.x, lo.y, hi.x, hi.y);
    }
}

// ---- main kernel: fp8 tables, K-remapped dwordx4 gathers, double-buffered
// gather pipeline (issue set k+1 while computing set k).

#define SIDX(k) (((k) * NBLOCKS + (int)blockIdx.x) * SPB + wave * 32 + l31)

#define GATHER6(n01, n23, f01, f23, m01, m23, in_, im_, if__) do {            \
    const unsigned char* pn_ = nci8 + (long)(in_) * 64 + hoff;                \
    const unsigned char* pf_ = fma8 + (long)(if__) * 64 + hoff;               \
    const unsigned char* pm_ = nci8 + (long)(im_) * 64 + hoff;                \
    n01 = *(const ulonglong2*)pn_;  n23 = *(const ulonglong2*)(pn_ + 16);     \
    f01 = *(const ulonglong2*)pf_;  f23 = *(const ulonglong2*)(pf_ + 16);     \
    m01 = *(const ulonglong2*)pm_;  m23 = *(const ulonglong2*)(pm_ + 16);     \
} while (0)

#define COMPUTE6(n01, n23, f01, f23, m01, m23) do {                           \
    const long An_[4] = {(long)n01.x, (long)n01.y, (long)n23.x, (long)n23.y}; \
    const long Ff_[4] = {(long)f01.x, (long)f01.y, (long)f23.x, (long)f23.y}; \
    const long Am_[4] = {(long)m01.x, (long)m01.y, (long)m23.x, (long)m23.y}; \
    {   floatx16 a{};                                                         \
        _Pragma("unroll")                                                     \
        for (int t = 0; t < 4; ++t)                                           \
            a = __builtin_amdgcn_mfma_f32_32x32x16_fp8_fp8(An_[t], Bn[0][t], a, 0, 0, 0); \
        _Pragma("unroll")                                                     \
        for (int t = 0; t < 4; ++t)                                           \
            a = __builtin_amdgcn_mfma_f32_32x32x16_fp8_fp8(Ff_[t], If0[t], a, 0, 0, 0);   \
        _Pragma("unroll")                                                     \
        for (int r = 0; r < 16; r += 4) {                                     \
            l0 = fmaf(a[r],     a[r],     l0);                                \
            l1 = fmaf(a[r + 1], a[r + 1], l1);                                \
            l2 = fmaf(a[r + 2], a[r + 2], l2);                                \
            l3 = fmaf(a[r + 3], a[r + 3], l3);                                \
        }                                                                     \
    }                                                                         \
    {   floatx16 a{};                                                         \
        _Pragma("unroll")                                                     \
        for (int t = 0; t < 4; ++t)                                           \
            a = __builtin_amdgcn_mfma_f32_32x32x16_fp8_fp8(An_[t], Bn[1][t], a, 0, 0, 0); \
        _Pragma("unroll")                                                     \
        for (int t = 0; t < 4; ++t)                                           \
            a = __builtin_amdgcn_mfma_f32_32x32x16_fp8_fp8(Ff_[t], If1[t], a, 0, 0, 0);   \
        _Pragma("unroll")                                                     \
        for (int r = 0; r < 16; r += 4) {                                     \
            l0 = fmaf(a[r],     a[r],     l0);                                \
            l1 = fmaf(a[r + 1], a[r + 1], l1);                                \
            l2 = fmaf(a[r + 2], a[r + 2], l2);                                \
            l3 = fmaf(a[r + 3], a[r + 3], l3);                                \
        }                                                                     \
    }                                                                         \
    {   floatx16 a{};                                                         \
        _Pragma("unroll")                                                     \
        for (int t = 0; t < 4; ++t)                                           \
            a = __builtin_amdgcn_mfma_f32_32x32x16_fp8_fp8(Am_[t], Bm[0][t], a, 0, 0, 0); \
        _Pragma("unroll")                                                     \
        for (int t = 0; t < 4; ++t)                                           \
            a = __builtin_amdgcn_mfma_f32_32x32x16_fp8_fp8(Ff_[t], If0[t], a, 0, 0, 0);   \
        _Pragma("unroll")                                                     \
        for (int r = 0; r < 16; r += 4) {                                     \
            l0 = fmaf(a[r],     a[r],     l0);                                \
            l1 = fmaf(a[r + 1], a[r + 1], l1);                                \
            l2 = fmaf(a[r + 2], a[r + 2], l2);                                \
            l3 = fmaf(a[r + 3], a[r + 3], l3);                                \
        }                                                                     \
    }                                                                         \
    {   floatx16 a{};                                                         \
        _Pragma("unroll")                                                     \
        for (int t = 0; t < 4; ++t)                                           \
            a = __builtin_amdgcn_mfma_f32_32x32x16_fp8_fp8(Am_[t], Bm[1][t], a, 0, 0, 0); \
        _Pragma("unroll")                                                     \
        for (int t = 0; t < 4; ++t)                                           \
            a = __builtin_amdgcn_mfma_f32_32x32x16_fp8_fp8(Ff_[t], If1[t], a, 0, 0, 0);   \
        _Pragma("unroll")                                                     \
        for (int r = 0; r < 16; r += 4) {                                     \
            l0 = fmaf(a[r],     a[r],     l0);                                \
            l1 = fmaf(a[r + 1], a[r + 1], l1);                                \
            l2 = fmaf(a[r + 2], a[r + 2], l2);                                \
            l3 = fmaf(a[r + 3], a[r + 3], l3);                                \
        }                                                                     \
    }                                                                         \
} while (0)

__global__ __launch_bounds__(256, 4) void ontomap_kernel_q(
    const int* __restrict__ pos_n, const int* __restrict__ pos_m,
    const int* __restrict__ pos_f,
    const unsigned char* __restrict__ nci8, const unsigned char* __restrict__ fma8,
    const long* __restrict__ fragN, const long* __restrict__ fragM,
    float* __restrict__ out, int iters)
{
    const int lane = threadIdx.x & 63;
    const int wave = threadIdx.x >> 6;
    const int l31  = lane & 31;
    const int hi   = lane >> 5;
    const int hoff = hi * 32;     // this lane's contiguous 32-byte half-row

    // B fragments (precomputed in convert_kernel): 16 coalesced L2-hit loads.
    long Bn[2][4], Bm[2][4];
#pragma unroll
    for (int nt = 0; nt < 2; ++nt) {
#pragma unroll
        for (int t = 0; t < 4; ++t) {
            Bn[nt][t] = fragN[(nt * 4 + t) * 64 + lane];
            Bm[nt][t] = fragM[(nt * 4 + t) * 64 + lane];
        }
    }

    // -I fragments (fp8 0xB8 = -1.0 e4m3). Step t has -1 at byte j = l31-t*8
    // when 0 <= j < 8; tile0's diagonal in hi=0 slots, tile1's in hi=1.
    long If0[4], If1[4];
#pragma unroll
    for (int t = 0; t < 4; ++t) {
        const unsigned j = (unsigned)(l31 - t * 8);
        const long pat = (j < 8) ? (long)(0xB8ULL << (8 * j)) : 0L;
        If0[t] = hi ? 0L : pat;
        If1[t] = hi ? pat : 0L;
    }

    float l0 = 0.0f, l1 = 0.0f, l2 = 0.0f, l3 = 0.0f;

    // ---- double-buffered gather pipeline.
    ulonglong2 An01, An23, Af01, Af23, Am01, Am23;   // set A
    ulonglong2 Bq01, Bq23, Bf01, Bf23, Bm01, Bm23;   // set B

    int inA, imA, ifA, inB = 0, imB = 0, ifB = 0;
    {
        const int s = SIDX(0);
        inA = pos_n[s]; imA = pos_m[s]; ifA = pos_f[s];
    }
    GATHER6(An01, An23, Af01, Af23, Am01, Am23, inA, imA, ifA);
    if (iters > 1) {
        const int s = SIDX(1);
        inB = pos_n[s]; imB = pos_m[s]; ifB = pos_f[s];
    }

#pragma unroll 1
    for (int it = 0; it < iters; it += 2) {
        if (it + 1 < iters)
            GATHER6(Bq01, Bq23, Bf01, Bf23, Bm01, Bm23, inB, imB, ifB);
        if (it + 2 < iters) {
            const int s = SIDX(it + 2);
            inA = pos_n[s]; imA = pos_m[s]; ifA = pos_f[s];
        }
        COMPUTE6(An01, An23, Af01, Af23, Am01, Am23);
        if (it + 2 < iters)
            GATHER6(An01, An23, Af01, Af23, Am01, Am23, inA, imA, ifA);
        if (it + 3 < iters) {
            const int s = SIDX(it + 3);
            inB = pos_n[s]; imB = pos_m[s]; ifB = pos_f[s];
        }
        if (it + 1 < iters)
            COMPUTE6(Bq01, Bq23, Bf01, Bf23, Bm01, Bm23);
    }

    float loss = (l0 + l1) + (l2 + l3);
#pragma unroll
    for (int o = 32; o > 0; o >>= 1) loss += __shfl_xor(loss, o, 64);

    // block-level reduction: 1 atomic per block instead of 4.
    __shared__ float red[4];
    if (lane == 0) red[wave] = loss;
    __syncthreads();
    if (threadIdx.x == 0)
        atomicAdd(out, (red[0] + red[1]) + (red[2] + red[3]));
}

// ---- fallback: fp32 tables with LDS staging (round-4 style), if ws too small.
#define ROW_BYTES 144
__global__ __launch_bounds__(256, 2) void ontomap_kernel_f32(
    const int* __restrict__ pos_n, const int* __restrict__ pos_m,
    const int* __restrict__ pos_f,
    const float* __restrict__ nci, const float* __restrict__ fma_emb,
    const float* __restrict__ n2f, const float* __restrict__ m2f,
    float* __restrict__ out, int iters)
{
    __shared__ char lds[4 * 2 * 32 * ROW_BYTES];

    const int lane = threadIdx.x & 63;
    const int wave = threadIdx.x >> 6;
    const int l31  = lane & 31;
    const int hi   = lane >> 5;
    const int kbase = hi * 8;
    const int srow   = lane >> 4;
    const int schunk = lane & 15;

    char* const nbase = lds + wave * (2 * 32 * ROW_BYTES);
    char* const mbase = nbase + 32 * ROW_BYTES;

    half8 Bn[2][4], Bm[2][4];
#pragma unroll
    for (int nt = 0; nt < 2; ++nt) {
#pragma unroll
        for (int t = 0; t < 4; ++t) {
            const float* p = n2f + (nt * 32 + l31) * 64 + t * 16 + kbase;
            Bn[nt][t] = cvt8(*(const float4*)p, *(const float4*)(p + 4));
            const float* q = m2f + (nt * 32 + l31) * 64 + t * 16 + kbase;
            Bm[nt][t] = cvt8(*(const float4*)q, *(const float4*)(q + 4));
        }
    }

    float loss = 0.0f;
    int in_, im_, if_;
    {
        int s = blockIdx.x * SPB + wave * 32 + l31;
        in_ = pos_n[s]; im_ = pos_m[s]; if_ = pos_f[s];
    }

#pragma unroll 1
    for (int it = 0; it < iters; ++it) {
        const int in0 = in_, im0 = im_, if0 = if_;
        if (it + 1 < iters) {
            int s = ((it + 1) * NBLOCKS + blockIdx.x) * SPB + wave * 32 + l31;
            in_ = pos_n[s]; im_ = pos_m[s]; if_ = pos_f[s];
        }

#pragma unroll
        for (int i = 0; i < 8; ++i) {
            const int rl = i * 4 + srow;
            const int rn = __shfl(in0, rl, 64);
            float4 v = ((const float4*)(nci + (long)rn * 64))[schunk];
            *(uint2*)(nbase + rl * ROW_BYTES + schunk * 8) = pack4(v);
            const int rm = __shfl(im0, rl, 64);
            float4 w = ((const float4*)(nci + (long)rm * 64))[schunk];
            *(uint2*)(mbase + rl * ROW_BYTES + schunk * 8) = pack4(w);
        }
        asm volatile("" ::: "memory");

        floatx16 aN0{}, aN1{}, aM0{}, aM1{};
#pragma unroll
        for (int t = 0; t < 4; ++t) {
            half8 aF = *(const half8*)(nbase + l31 * ROW_BYTES + t * 32 + hi * 16);
            aN0 = __builtin_amdgcn_mfma_f32_32x32x16_f16(aF, Bn[0][t], aN0, 0, 0, 0);
            aN1 = __builtin_amdgcn_mfma_f32_32x32x16_f16(aF, Bn[1][t], aN1, 0, 0, 0);
            half8 bF = *(const half8*)(mbase + l31 * ROW_BYTES + t * 32 + hi * 16);
            aM0 = __builtin_amdgcn_mfma_f32_32x32x16_f16(bF, Bm[0][t], aM0, 0, 0, 0);
            aM1 = __builtin_amdgcn_mfma_f32_32x32x16_f16(bF, Bm[1][t], aM1, 0, 0, 0);
        }

#pragma unroll
        for (int r = 0; r < 16; ++r) {
            const int mrow = (r & 3) + 8 * (r >> 2) + 4 * hi;
            const int fid  = __shfl(if0, mrow, 64);
            const float* pf = fma_emb + (long)fid * 64 + l31;
            const float f0 = pf[0];
            const float f1 = pf[32];
            float d;
            d = aN0[r] - f0; loss = fmaf(d, d, loss);
            d = aM0[r] - f0; loss = fmaf(d, d, loss);
            d = aN1[r] - f1; loss = fmaf(d, d, loss);
            d = aM1[r] - f1; loss = fmaf(d, d, loss);
        }
    }

#pragma unroll
    for (int o = 32; o > 0; o >>= 1) loss += __shfl_xor(loss, o, 64);
    if (lane == 0) atomicAdd(out, loss);
}

extern "C" void kernel_launch(void* const* d_in, const int* in_sizes, int n_in,
                              void* d_out, int out_size, void* d_ws, size_t ws_size,
                              hipStream_t stream) {
    const int*   pos_n   = (const int*)d_in[0];
    const int*   pos_m   = (const int*)d_in[1];
    const int*   pos_f   = (const int*)d_in[2];
    const float* nci_emb = (const float*)d_in[3];
    const float* fma_emb = (const float*)d_in[4];
    const float* n2f_mat = (const float*)d_in[5];
    const float* m2f_mat = (const float*)d_in[6];
    float* out = (float*)d_out;

    const int B = in_sizes[0];
    const int iters = B / (NBLOCKS * SPB);  // 1,048,576 -> 4

    const size_t TBL  = (size_t)NCI_ELEMS + (size_t)FMA_ELEMS;          // 16,000,000
    const size_t need = TBL + (size_t)FRAG_LONGS * sizeof(long);        // +8 KB
    if (ws_size >= need) {
        unsigned char* nci8 = (unsigned char*)d_ws;
        unsigned char* fma8 = nci8 + NCI_ELEMS;   // 9,600,000 is 64B-aligned
        long* fragN = (long*)(nci8 + TBL);        // 16,000,000 is 64B-aligned
        long* fragM = fragN + 8 * 64;
        convert_kernel<<<2048, 256, 0, stream>>>(
            (const float4*)nci_emb, (const float4*)fma_emb,
            (uint4*)nci8, (uint4*)fma8, out, n2f_mat, m2f_mat, fragN, fragM);
        ontomap_kernel_q<<<NBLOCKS, 256, 0, stream>>>(
            pos_n, pos_m, pos_f, nci8, fma8, fragN, fragM, out, iters);
    } else {
        (void)hipMemsetAsync(out, 0, sizeof(float), stream);
        ontomap_kernel_f32<<<NBLOCKS, 256, 0, stream>>>(
            pos_n, pos_m, pos_f, nci_emb, fma_emb, n2f_mat, m2f_mat, out, iters);
    }
}

// Round 8
// 193.955 us; speedup vs baseline: 1.3355x; 1.3355x over previous
//
#include <hip/hip_runtime.h>
#include <hip/hip_fp16.h>

// Ontomap: loss = sum((n2f@n_e - f_e)^2) + sum((m2f@m_e - f_e)^2)
// B = 1,048,576, D = 64.
// Round 18: R17's gather double-buffer with the register budget actually
// sized for it. Unified VGPR+AGPR budget = 512/min_waves_per_EU:
// (256,4) -> 128/wave (64 AGPR + 64 VGPR) -- R16 fits exactly, R17's +24
// VGPR spilled 197MB to scratch. (256,3) -> ~170/wave: R17's ~152 fits.
// Residency cap 16 -> 12 waves/CU (measured effective was ~10 anyway);
// per-wave in-flight gather lines double 6 -> 12. Code otherwise identical
// to R17 (which passed correctness).

typedef _Float16 half8 __attribute__((ext_vector_type(8)));
typedef __fp16  fp16x2 __attribute__((ext_vector_type(2)));
typedef float floatx16 __attribute__((ext_vector_type(16)));

#define NBLOCKS 2048
#define SPB 128                 // samples per block-iteration: 4 waves * 32
#define NCI_ELEMS 9600000       // 150000 * 64
#define FMA_ELEMS 6400000       // 100000 * 64
#define FRAG_LONGS 512          // 2 matrices * 8 frags * 64 lanes

__device__ inline half8 cvt8(float4 a, float4 b) {
    union { half8 h; fp16x2 h2[4]; } u;
    u.h2[0] = __builtin_amdgcn_cvt_pkrtz(a.x, a.y);
    u.h2[1] = __builtin_amdgcn_cvt_pkrtz(a.z, a.w);
    u.h2[2] = __builtin_amdgcn_cvt_pkrtz(b.x, b.y);
    u.h2[3] = __builtin_amdgcn_cvt_pkrtz(b.z, b.w);
    return u.h;
}

__device__ inline uint2 pack4(float4 v) {
    union { fp16x2 h2[2]; uint2 u; } p;
    p.h2[0] = __builtin_amdgcn_cvt_pkrtz(v.x, v.y);
    p.h2[1] = __builtin_amdgcn_cvt_pkrtz(v.z, v.w);
    return p.u;
}

// 8 fp32 -> 8 fp8-e4m3 bytes (ascending order).
__device__ inline uint2 pack8_fp8(float4 a, float4 b) {
    int lo = 0, hi = 0;
    lo = __builtin_amdgcn_cvt_pk_fp8_f32(a.x, a.y, lo, false);
    lo = __builtin_amdgcn_cvt_pk_fp8_f32(a.z, a.w, lo, true);
    hi = __builtin_amdgcn_cvt_pk_fp8_f32(b.x, b.y, hi, false);
    hi = __builtin_amdgcn_cvt_pk_fp8_f32(b.z, b.w, hi, true);
    uint2 r; r.x = (unsigned)lo; r.y = (unsigned)hi; return r;
}

__device__ inline long pack8_fp8_l(const float* p) {
    uint2 b = pack8_fp8(*(const float4*)p, *(const float4*)(p + 4));
    return (long)(((unsigned long)b.y << 32) | b.x);
}

// ---- streaming conversion: both tables -> fp8, into workspace.
// Also zeroes the loss accumulator and precomputes the per-lane packed
// B-fragments for both matrices (frag[(nt*4+t)*64 + lane], 8KB total).
__global__ __launch_bounds__(256) void convert_kernel(
    const float4* __restrict__ nci, const float4* __restrict__ fma,
    uint4* __restrict__ nci8, uint4* __restrict__ fma8, float* __restrict__ out,
    const float* __restrict__ n2f, const float* __restrict__ m2f,
    long* __restrict__ fragN, long* __restrict__ fragM)
{
    const int stride = gridDim.x * blockDim.x;
    const int tid = blockIdx.x * blockDim.x + threadIdx.x;
    if (tid == 0) out[0] = 0.0f;
    if (blockIdx.x == 0 && threadIdx.x < 64) {
        const int lane = threadIdx.x;
        const int l31 = lane & 31;
        const int hoff = (lane >> 5) * 32;
#pragma unroll
        for (int nt = 0; nt < 2; ++nt) {
#pragma unroll
            for (int t = 0; t < 4; ++t) {
                fragN[(nt * 4 + t) * 64 + lane] =
                    pack8_fp8_l(n2f + (nt * 32 + l31) * 64 + hoff + t * 8);
                fragM[(nt * 4 + t) * 64 + lane] =
                    pack8_fp8_l(m2f + (nt * 32 + l31) * 64 + hoff + t * 8);
            }
        }
    }
    for (int i = tid; i < NCI_ELEMS / 16; i += stride) {
        uint2 lo = pack8_fp8(nci[4 * i],     nci[4 * i + 1]);
        uint2 hi = pack8_fp8(nci[4 * i + 2], nci[4 * i + 3]);
        nci8[i] = make_uint4(lo.x, lo.y, hi.x, hi.y);
    }
    for (int i = tid; i < FMA_ELEMS / 16; i += stride) {
        uint2 lo = pack8_fp8(fma[4 * i],     fma[4 * i + 1]);
        uint2 hi = pack8_fp8(fma[4 * i + 2], fma[4 * i + 3]);
        fma8[i] = make_uint4(lo.x, lo.y, hi.x, hi.y);
    }
}

// ---- main kernel: fp8 tables, K-remapped dwordx4 gathers, double-buffered
// gather pipeline (issue set k+1 while computing set k).

#define SIDX(k) (((k) * NBLOCKS + (int)blockIdx.x) * SPB + wave * 32 + l31)

#define GATHER6(n01, n23, f01, f23, m01, m23, in_, im_, if__) do {            \
    const unsigned char* pn_ = nci8 + (long)(in_) * 64 + hoff;                \
    const unsigned char* pf_ = fma8 + (long)(if__) * 64 + hoff;               \
    const unsigned char* pm_ = nci8 + (long)(im_) * 64 + hoff;                \
    n01 = *(const ulonglong2*)pn_;  n23 = *(const ulonglong2*)(pn_ + 16);     \
    f01 = *(const ulonglong2*)pf_;  f23 = *(const ulonglong2*)(pf_ + 16);     \
    m01 = *(const ulonglong2*)pm_;  m23 = *(const ulonglong2*)(pm_ + 16);     \
} while (0)

#define COMPUTE6(n01, n23, f01, f23, m01, m23) do {                           \
    const long An_[4] = {(long)n01.x, (long)n01.y, (long)n23.x, (long)n23.y}; \
    const long Ff_[4] = {(long)f01.x, (long)f01.y, (long)f23.x, (long)f23.y}; \
    const long Am_[4] = {(long)m01.x, (long)m01.y, (long)m23.x, (long)m23.y}; \
    {   floatx16 a{};                                                         \
        _Pragma("unroll")                                                     \
        for (int t = 0; t < 4; ++t)                                           \
            a = __builtin_amdgcn_mfma_f32_32x32x16_fp8_fp8(An_[t], Bn[0][t], a, 0, 0, 0); \
        _Pragma("unroll")                                                     \
        for (int t = 0; t < 4; ++t)                                           \
            a = __builtin_amdgcn_mfma_f32_32x32x16_fp8_fp8(Ff_[t], If0[t], a, 0, 0, 0);   \
        _Pragma("unroll")                                                     \
        for (int r = 0; r < 16; r += 4) {                                     \
            l0 = fmaf(a[r],     a[r],     l0);                                \
            l1 = fmaf(a[r + 1], a[r + 1], l1);                                \
            l2 = fmaf(a[r + 2], a[r + 2], l2);                                \
            l3 = fmaf(a[r + 3], a[r + 3], l3);                                \
        }                                                                     \
    }                                                                         \
    {   floatx16 a{};                                                         \
        _Pragma("unroll")                                                     \
        for (int t = 0; t < 4; ++t)                                           \
            a = __builtin_amdgcn_mfma_f32_32x32x16_fp8_fp8(An_[t], Bn[1][t], a, 0, 0, 0); \
        _Pragma("unroll")                                                     \
        for (int t = 0; t < 4; ++t)                                           \
            a = __builtin_amdgcn_mfma_f32_32x32x16_fp8_fp8(Ff_[t], If1[t], a, 0, 0, 0);   \
        _Pragma("unroll")                                                     \
        for (int r = 0; r < 16; r += 4) {                                     \
            l0 = fmaf(a[r],     a[r],     l0);                                \
            l1 = fmaf(a[r + 1], a[r + 1], l1);                                \
            l2 = fmaf(a[r + 2], a[r + 2], l2);                                \
            l3 = fmaf(a[r + 3], a[r + 3], l3);                                \
        }                                                                     \
    }                                                                         \
    {   floatx16 a{};                                                         \
        _Pragma("unroll")                                                     \
        for (int t = 0; t < 4; ++t)                                           \
            a = __builtin_amdgcn_mfma_f32_32x32x16_fp8_fp8(Am_[t], Bm[0][t], a, 0, 0, 0); \
        _Pragma("unroll")                                                     \
        for (int t = 0; t < 4; ++t)                                           \
            a = __builtin_amdgcn_mfma_f32_32x32x16_fp8_fp8(Ff_[t], If0[t], a, 0, 0, 0);   \
        _Pragma("unroll")                                                     \
        for (int r = 0; r < 16; r += 4) {                                     \
            l0 = fmaf(a[r],     a[r],     l0);                                \
            l1 = fmaf(a[r + 1], a[r + 1], l1);                                \
            l2 = fmaf(a[r + 2], a[r + 2], l2);                                \
            l3 = fmaf(a[r + 3], a[r + 3], l3);                                \
        }                                                                     \
    }                                                                         \
    {   floatx16 a{};                                                         \
        _Pragma("unroll")                                                     \
        for (int t = 0; t < 4; ++t)                                           \
            a = __builtin_amdgcn_mfma_f32_32x32x16_fp8_fp8(Am_[t], Bm[1][t], a, 0, 0, 0); \
        _Pragma("unroll")                                                     \
        for (int t = 0; t < 4; ++t)                                           \
            a = __builtin_amdgcn_mfma_f32_32x32x16_fp8_fp8(Ff_[t], If1[t], a, 0, 0, 0);   \
        _Pragma("unroll")                                                     \
        for (int r = 0; r < 16; r += 4) {                                     \
            l0 = fmaf(a[r],     a[r],     l0);                                \
            l1 = fmaf(a[r + 1], a[r + 1], l1);                                \
            l2 = fmaf(a[r + 2], a[r + 2], l2);                                \
            l3 = fmaf(a[r + 3], a[r + 3], l3);                                \
        }                                                                     \
    }                                                                         \
} while (0)

__global__ __launch_bounds__(256, 3) void ontomap_kernel_q(
    const int* __restrict__ pos_n, const int* __restrict__ pos_m,
    const int* __restrict__ pos_f,
    const unsigned char* __restrict__ nci8, const unsigned char* __restrict__ fma8,
    const long* __restrict__ fragN, const long* __restrict__ fragM,
    float* __restrict__ out, int iters)
{
    const int lane = threadIdx.x & 63;
    const int wave = threadIdx.x >> 6;
    const int l31  = lane & 31;
    const int hi   = lane >> 5;
    const int hoff = hi * 32;     // this lane's contiguous 32-byte half-row

    // B fragments (precomputed in convert_kernel): 16 coalesced L2-hit loads.
    long Bn[2][4], Bm[2][4];
#pragma unroll
    for (int nt = 0; nt < 2; ++nt) {
#pragma unroll
        for (int t = 0; t < 4; ++t) {
            Bn[nt][t] = fragN[(nt * 4 + t) * 64 + lane];
            Bm[nt][t] = fragM[(nt * 4 + t) * 64 + lane];
        }
    }

    // -I fragments (fp8 0xB8 = -1.0 e4m3). Step t has -1 at byte j = l31-t*8
    // when 0 <= j < 8; tile0's diagonal in hi=0 slots, tile1's in hi=1.
    long If0[4], If1[4];
#pragma unroll
    for (int t = 0; t < 4; ++t) {
        const unsigned j = (unsigned)(l31 - t * 8);
        const long pat = (j < 8) ? (long)(0xB8ULL << (8 * j)) : 0L;
        If0[t] = hi ? 0L : pat;
        If1[t] = hi ? pat : 0L;
    }

    float l0 = 0.0f, l1 = 0.0f, l2 = 0.0f, l3 = 0.0f;

    // ---- double-buffered gather pipeline.
    ulonglong2 An01, An23, Af01, Af23, Am01, Am23;   // set A
    ulonglong2 Bq01, Bq23, Bf01, Bf23, Bm01, Bm23;   // set B

    int inA, imA, ifA, inB = 0, imB = 0, ifB = 0;
    {
        const int s = SIDX(0);
        inA = pos_n[s]; imA = pos_m[s]; ifA = pos_f[s];
    }
    GATHER6(An01, An23, Af01, Af23, Am01, Am23, inA, imA, ifA);
    if (iters > 1) {
        const int s = SIDX(1);
        inB = pos_n[s]; imB = pos_m[s]; ifB = pos_f[s];
    }

#pragma unroll 1
    for (int it = 0; it < iters; it += 2) {
        if (it + 1 < iters)
            GATHER6(Bq01, Bq23, Bf01, Bf23, Bm01, Bm23, inB, imB, ifB);
        if (it + 2 < iters) {
            const int s = SIDX(it + 2);
            inA = pos_n[s]; imA = pos_m[s]; ifA = pos_f[s];
        }
        COMPUTE6(An01, An23, Af01, Af23, Am01, Am23);
        if (it + 2 < iters)
            GATHER6(An01, An23, Af01, Af23, Am01, Am23, inA, imA, ifA);
        if (it + 3 < iters) {
            const int s = SIDX(it + 3);
            inB = pos_n[s]; imB = pos_m[s]; ifB = pos_f[s];
        }
        if (it + 1 < iters)
            COMPUTE6(Bq01, Bq23, Bf01, Bf23, Bm01, Bm23);
    }

    float loss = (l0 + l1) + (l2 + l3);
#pragma unroll
    for (int o = 32; o > 0; o >>= 1) loss += __shfl_xor(loss, o, 64);

    // block-level reduction: 1 atomic per block instead of 4.
    __shared__ float red[4];
    if (lane == 0) red[wave] = loss;
    __syncthreads();
    if (threadIdx.x == 0)
        atomicAdd(out, (red[0] + red[1]) + (red[2] + red[3]));
}

// ---- fallback: fp32 tables with LDS staging (round-4 style), if ws too small.
#define ROW_BYTES 144
__global__ __launch_bounds__(256, 2) void ontomap_kernel_f32(
    const int* __restrict__ pos_n, const int* __restrict__ pos_m,
    const int* __restrict__ pos_f,
    const float* __restrict__ nci, const float* __restrict__ fma_emb,
    const float* __restrict__ n2f, const float* __restrict__ m2f,
    float* __restrict__ out, int iters)
{
    __shared__ char lds[4 * 2 * 32 * ROW_BYTES];

    const int lane = threadIdx.x & 63;
    const int wave = threadIdx.x >> 6;
    const int l31  = lane & 31;
    const int hi   = lane >> 5;
    const int kbase = hi * 8;
    const int srow   = lane >> 4;
    const int schunk = lane & 15;

    char* const nbase = lds + wave * (2 * 32 * ROW_BYTES);
    char* const mbase = nbase + 32 * ROW_BYTES;

    half8 Bn[2][4], Bm[2][4];
#pragma unroll
    for (int nt = 0; nt < 2; ++nt) {
#pragma unroll
        for (int t = 0; t < 4; ++t) {
            const float* p = n2f + (nt * 32 + l31) * 64 + t * 16 + kbase;
            Bn[nt][t] = cvt8(*(const float4*)p, *(const float4*)(p + 4));
            const float* q = m2f + (nt * 32 + l31) * 64 + t * 16 + kbase;
            Bm[nt][t] = cvt8(*(const float4*)q, *(const float4*)(q + 4));
        }
    }

    float loss = 0.0f;
    int in_, im_, if_;
    {
        int s = blockIdx.x * SPB + wave * 32 + l31;
        in_ = pos_n[s]; im_ = pos_m[s]; if_ = pos_f[s];
    }

#pragma unroll 1
    for (int it = 0; it < iters; ++it) {
        const int in0 = in_, im0 = im_, if0 = if_;
        if (it + 1 < iters) {
            int s = ((it + 1) * NBLOCKS + blockIdx.x) * SPB + wave * 32 + l31;
            in_ = pos_n[s]; im_ = pos_m[s]; if_ = pos_f[s];
        }

#pragma unroll
        for (int i = 0; i < 8; ++i) {
            const int rl = i * 4 + srow;
            const int rn = __shfl(in0, rl, 64);
            float4 v = ((const float4*)(nci + (long)rn * 64))[schunk];
            *(uint2*)(nbase + rl * ROW_BYTES + schunk * 8) = pack4(v);
            const int rm = __shfl(im0, rl, 64);
            float4 w = ((const float4*)(nci + (long)rm * 64))[schunk];
            *(uint2*)(mbase + rl * ROW_BYTES + schunk * 8) = pack4(w);
        }
        asm volatile("" ::: "memory");

        floatx16 aN0{}, aN1{}, aM0{}, aM1{};
#pragma unroll
        for (int t = 0; t < 4; ++t) {
            half8 aF = *(const half8*)(nbase + l31 * ROW_BYTES + t * 32 + hi * 16);
            aN0 = __builtin_amdgcn_mfma_f32_32x32x16_f16(aF, Bn[0][t], aN0, 0, 0, 0);
            aN1 = __builtin_amdgcn_mfma_f32_32x32x16_f16(aF, Bn[1][t], aN1, 0, 0, 0);
            half8 bF = *(const half8*)(mbase + l31 * ROW_BYTES + t * 32 + hi * 16);
            aM0 = __builtin_amdgcn_mfma_f32_32x32x16_f16(bF, Bm[0][t], aM0, 0, 0, 0);
            aM1 = __builtin_amdgcn_mfma_f32_32x32x16_f16(bF, Bm[1][t], aM1, 0, 0, 0);
        }

#pragma unroll
        for (int r = 0; r < 16; ++r) {
            const int mrow = (r & 3) + 8 * (r >> 2) + 4 * hi;
            const int fid  = __shfl(if0, mrow, 64);
            const float* pf = fma_emb + (long)fid * 64 + l31;
            const float f0 = pf[0];
            const float f1 = pf[32];
            float d;
            d = aN0[r] - f0; loss = fmaf(d, d, loss);
            d = aM0[r] - f0; loss = fmaf(d, d, loss);
            d = aN1[r] - f1; loss = fmaf(d, d, loss);
            d = aM1[r] - f1; loss = fmaf(d, d, loss);
        }
    }

#pragma unroll
    for (int o = 32; o > 0; o >>= 1) loss += __shfl_xor(loss, o, 64);
    if (lane == 0) atomicAdd(out, loss);
}

extern "C" void kernel_launch(void* const* d_in, const int* in_sizes, int n_in,
                              void* d_out, int out_size, void* d_ws, size_t ws_size,
                              hipStream_t stream) {
    const int*   pos_n   = (const int*)d_in[0];
    const int*   pos_m   = (const int*)d_in[1];
    const int*   pos_f   = (const int*)d_in[2];
    const float* nci_emb = (const float*)d_in[3];
    const float* fma_emb = (const float*)d_in[4];
    const float* n2f_mat = (const float*)d_in[5];
    const float* m2f_mat = (const float*)d_in[6];
    float* out = (float*)d_out;

    const int B = in_sizes[0];
    const int iters = B / (NBLOCKS * SPB);  // 1,048,576 -> 4

    const size_t TBL  = (size_t)NCI_ELEMS + (size_t)FMA_ELEMS;          // 16,000,000
    const size_t need = TBL + (size_t)FRAG_LONGS * sizeof(long);        // +8 KB
    if (ws_size >= need) {
        unsigned char* nci8 = (unsigned char*)d_ws;
        unsigned char* fma8 = nci8 + NCI_ELEMS;   // 9,600,000 is 64B-aligned
        long* fragN = (long*)(nci8 + TBL);        // 16,000,000 is 64B-aligned
        long* fragM = fragN + 8 * 64;
        convert_kernel<<<2048, 256, 0, stream>>>(
            (const float4*)nci_emb, (const float4*)fma_emb,
            (uint4*)nci8, (uint4*)fma8, out, n2f_mat, m2f_mat, fragN, fragM);
        ontomap_kernel_q<<<NBLOCKS, 256, 0, stream>>>(
            pos_n, pos_m, pos_f, nci8, fma8, fragN, fragM, out, iters);
    } else {
        (void)hipMemsetAsync(out, 0, sizeof(float), stream);
        ontomap_kernel_f32<<<NBLOCKS, 256, 0, stream>>>(
            pos_n, pos_m, pos_f, nci_emb, fma_emb, n2f_mat, m2f_mat, out, iters);
    }
}

// Round 9
// 158.667 us; speedup vs baseline: 1.6325x; 1.2224x over previous
//
#include <hip/hip_runtime.h>
#include <hip/hip_fp16.h>

// Ontomap: loss = sum((n2f@n_e - f_e)^2) + sum((m2f@m_e - f_e)^2)
// B = 1,048,576, D = 64.
// Round 19: the double-buffer sized with an HONEST register budget.
// Spill ledger: (256,4)=128 regs -> R17 spilled; (256,3)=~170 split
// 84 arch + acc -> R18 still spilled (90us). The pipeline needs ~150 arch
// + 64 acc = ~215 regs. (256,2) gives 256/wave: fits with slack; HW then
// grants floor(512/~216)=2 waves/SIMD = 8 waves/CU x 12 in-flight lines =
// 96 lines/CU vs R16's ~60. Latency model (2.42M misses x ~700cy needs
// C>=52/CU at 53us) predicts main ~35-43us if concurrency is the limiter.
// Code identical to R17/R18 (correctness-verified) except launch bounds.

typedef _Float16 half8 __attribute__((ext_vector_type(8)));
typedef __fp16  fp16x2 __attribute__((ext_vector_type(2)));
typedef float floatx16 __attribute__((ext_vector_type(16)));

#define NBLOCKS 2048
#define SPB 128                 // samples per block-iteration: 4 waves * 32
#define NCI_ELEMS 9600000       // 150000 * 64
#define FMA_ELEMS 6400000       // 100000 * 64
#define FRAG_LONGS 512          // 2 matrices * 8 frags * 64 lanes

__device__ inline half8 cvt8(float4 a, float4 b) {
    union { half8 h; fp16x2 h2[4]; } u;
    u.h2[0] = __builtin_amdgcn_cvt_pkrtz(a.x, a.y);
    u.h2[1] = __builtin_amdgcn_cvt_pkrtz(a.z, a.w);
    u.h2[2] = __builtin_amdgcn_cvt_pkrtz(b.x, b.y);
    u.h2[3] = __builtin_amdgcn_cvt_pkrtz(b.z, b.w);
    return u.h;
}

__device__ inline uint2 pack4(float4 v) {
    union { fp16x2 h2[2]; uint2 u; } p;
    p.h2[0] = __builtin_amdgcn_cvt_pkrtz(v.x, v.y);
    p.h2[1] = __builtin_amdgcn_cvt_pkrtz(v.z, v.w);
    return p.u;
}

// 8 fp32 -> 8 fp8-e4m3 bytes (ascending order).
__device__ inline uint2 pack8_fp8(float4 a, float4 b) {
    int lo = 0, hi = 0;
    lo = __builtin_amdgcn_cvt_pk_fp8_f32(a.x, a.y, lo, false);
    lo = __builtin_amdgcn_cvt_pk_fp8_f32(a.z, a.w, lo, true);
    hi = __builtin_amdgcn_cvt_pk_fp8_f32(b.x, b.y, hi, false);
    hi = __builtin_amdgcn_cvt_pk_fp8_f32(b.z, b.w, hi, true);
    uint2 r; r.x = (unsigned)lo; r.y = (unsigned)hi; return r;
}

__device__ inline long pack8_fp8_l(const float* p) {
    uint2 b = pack8_fp8(*(const float4*)p, *(const float4*)(p + 4));
    return (long)(((unsigned long)b.y << 32) | b.x);
}

// ---- streaming conversion: both tables -> fp8, into workspace.
// Also zeroes the loss accumulator and precomputes the per-lane packed
// B-fragments for both matrices (frag[(nt*4+t)*64 + lane], 8KB total).
__global__ __launch_bounds__(256) void convert_kernel(
    const float4* __restrict__ nci, const float4* __restrict__ fma,
    uint4* __restrict__ nci8, uint4* __restrict__ fma8, float* __restrict__ out,
    const float* __restrict__ n2f, const float* __restrict__ m2f,
    long* __restrict__ fragN, long* __restrict__ fragM)
{
    const int stride = gridDim.x * blockDim.x;
    const int tid = blockIdx.x * blockDim.x + threadIdx.x;
    if (tid == 0) out[0] = 0.0f;
    if (blockIdx.x == 0 && threadIdx.x < 64) {
        const int lane = threadIdx.x;
        const int l31 = lane & 31;
        const int hoff = (lane >> 5) * 32;
#pragma unroll
        for (int nt = 0; nt < 2; ++nt) {
#pragma unroll
            for (int t = 0; t < 4; ++t) {
                fragN[(nt * 4 + t) * 64 + lane] =
                    pack8_fp8_l(n2f + (nt * 32 + l31) * 64 + hoff + t * 8);
                fragM[(nt * 4 + t) * 64 + lane] =
                    pack8_fp8_l(m2f + (nt * 32 + l31) * 64 + hoff + t * 8);
            }
        }
    }
    for (int i = tid; i < NCI_ELEMS / 16; i += stride) {
        uint2 lo = pack8_fp8(nci[4 * i],     nci[4 * i + 1]);
        uint2 hi = pack8_fp8(nci[4 * i + 2], nci[4 * i + 3]);
        nci8[i] = make_uint4(lo.x, lo.y, hi.x, hi.y);
    }
    for (int i = tid; i < FMA_ELEMS / 16; i += stride) {
        uint2 lo = pack8_fp8(fma[4 * i],     fma[4 * i + 1]);
        uint2 hi = pack8_fp8(fma[4 * i + 2], fma[4 * i + 3]);
        fma8[i] = make_uint4(lo.x, lo.y, hi.x, hi.y);
    }
}

// ---- main kernel: fp8 tables, K-remapped dwordx4 gathers, double-buffered
// gather pipeline (issue set k+1 while computing set k).

#define SIDX(k) (((k) * NBLOCKS + (int)blockIdx.x) * SPB + wave * 32 + l31)

#define GATHER6(n01, n23, f01, f23, m01, m23, in_, im_, if__) do {            \
    const unsigned char* pn_ = nci8 + (long)(in_) * 64 + hoff;                \
    const unsigned char* pf_ = fma8 + (long)(if__) * 64 + hoff;               \
    const unsigned char* pm_ = nci8 + (long)(im_) * 64 + hoff;                \
    n01 = *(const ulonglong2*)pn_;  n23 = *(const ulonglong2*)(pn_ + 16);     \
    f01 = *(const ulonglong2*)pf_;  f23 = *(const ulonglong2*)(pf_ + 16);     \
    m01 = *(const ulonglong2*)pm_;  m23 = *(const ulonglong2*)(pm_ + 16);     \
} while (0)

#define COMPUTE6(n01, n23, f01, f23, m01, m23) do {                           \
    const long An_[4] = {(long)n01.x, (long)n01.y, (long)n23.x, (long)n23.y}; \
    const long Ff_[4] = {(long)f01.x, (long)f01.y, (long)f23.x, (long)f23.y}; \
    const long Am_[4] = {(long)m01.x, (long)m01.y, (long)m23.x, (long)m23.y}; \
    {   floatx16 a{};                                                         \
        _Pragma("unroll")                                                     \
        for (int t = 0; t < 4; ++t)                                           \
            a = __builtin_amdgcn_mfma_f32_32x32x16_fp8_fp8(An_[t], Bn[0][t], a, 0, 0, 0); \
        _Pragma("unroll")                                                     \
        for (int t = 0; t < 4; ++t)                                           \
            a = __builtin_amdgcn_mfma_f32_32x32x16_fp8_fp8(Ff_[t], If0[t], a, 0, 0, 0);   \
        _Pragma("unroll")                                                     \
        for (int r = 0; r < 16; r += 4) {                                     \
            l0 = fmaf(a[r],     a[r],     l0);                                \
            l1 = fmaf(a[r + 1], a[r + 1], l1);                                \
            l2 = fmaf(a[r + 2], a[r + 2], l2);                                \
            l3 = fmaf(a[r + 3], a[r + 3], l3);                                \
        }                                                                     \
    }                                                                         \
    {   floatx16 a{};                                                         \
        _Pragma("unroll")                                                     \
        for (int t = 0; t < 4; ++t)                                           \
            a = __builtin_amdgcn_mfma_f32_32x32x16_fp8_fp8(An_[t], Bn[1][t], a, 0, 0, 0); \
        _Pragma("unroll")                                                     \
        for (int t = 0; t < 4; ++t)                                           \
            a = __builtin_amdgcn_mfma_f32_32x32x16_fp8_fp8(Ff_[t], If1[t], a, 0, 0, 0);   \
        _Pragma("unroll")                                                     \
        for (int r = 0; r < 16; r += 4) {                                     \
            l0 = fmaf(a[r],     a[r],     l0);                                \
            l1 = fmaf(a[r + 1], a[r + 1], l1);                                \
            l2 = fmaf(a[r + 2], a[r + 2], l2);                                \
            l3 = fmaf(a[r + 3], a[r + 3], l3);                                \
        }                                                                     \
    }                                                                         \
    {   floatx16 a{};                                                         \
        _Pragma("unroll")                                                     \
        for (int t = 0; t < 4; ++t)                                           \
            a = __builtin_amdgcn_mfma_f32_32x32x16_fp8_fp8(Am_[t], Bm[0][t], a, 0, 0, 0); \
        _Pragma("unroll")                                                     \
        for (int t = 0; t < 4; ++t)                                           \
            a = __builtin_amdgcn_mfma_f32_32x32x16_fp8_fp8(Ff_[t], If0[t], a, 0, 0, 0);   \
        _Pragma("unroll")                                                     \
        for (int r = 0; r < 16; r += 4) {                                     \
            l0 = fmaf(a[r],     a[r],     l0);                                \
            l1 = fmaf(a[r + 1], a[r + 1], l1);                                \
            l2 = fmaf(a[r + 2], a[r + 2], l2);                                \
            l3 = fmaf(a[r + 3], a[r + 3], l3);                                \
        }                                                                     \
    }                                                                         \
    {   floatx16 a{};                                                         \
        _Pragma("unroll")                                                     \
        for (int t = 0; t < 4; ++t)                                           \
            a = __builtin_amdgcn_mfma_f32_32x32x16_fp8_fp8(Am_[t], Bm[1][t], a, 0, 0, 0); \
        _Pragma("unroll")                                                     \
        for (int t = 0; t < 4; ++t)                                           \
            a = __builtin_amdgcn_mfma_f32_32x32x16_fp8_fp8(Ff_[t], If1[t], a, 0, 0, 0);   \
        _Pragma("unroll")                                                     \
        for (int r = 0; r < 16; r += 4) {                                     \
            l0 = fmaf(a[r],     a[r],     l0);                                \
            l1 = fmaf(a[r + 1], a[r + 1], l1);                                \
            l2 = fmaf(a[r + 2], a[r + 2], l2);                                \
            l3 = fmaf(a[r + 3], a[r + 3], l3);                                \
        }                                                                     \
    }                                                                         \
} while (0)

__global__ __launch_bounds__(256, 2) void ontomap_kernel_q(
    const int* __restrict__ pos_n, const int* __restrict__ pos_m,
    const int* __restrict__ pos_f,
    const unsigned char* __restrict__ nci8, const unsigned char* __restrict__ fma8,
    const long* __restrict__ fragN, const long* __restrict__ fragM,
    float* __restrict__ out, int iters)
{
    const int lane = threadIdx.x & 63;
    const int wave = threadIdx.x >> 6;
    const int l31  = lane & 31;
    const int hi   = lane >> 5;
    const int hoff = hi * 32;     // this lane's contiguous 32-byte half-row

    // B fragments (precomputed in convert_kernel): 16 coalesced L2-hit loads.
    long Bn[2][4], Bm[2][4];
#pragma unroll
    for (int nt = 0; nt < 2; ++nt) {
#pragma unroll
        for (int t = 0; t < 4; ++t) {
            Bn[nt][t] = fragN[(nt * 4 + t) * 64 + lane];
            Bm[nt][t] = fragM[(nt * 4 + t) * 64 + lane];
        }
    }

    // -I fragments (fp8 0xB8 = -1.0 e4m3). Step t has -1 at byte j = l31-t*8
    // when 0 <= j < 8; tile0's diagonal in hi=0 slots, tile1's in hi=1.
    long If0[4], If1[4];
#pragma unroll
    for (int t = 0; t < 4; ++t) {
        const unsigned j = (unsigned)(l31 - t * 8);
        const long pat = (j < 8) ? (long)(0xB8ULL << (8 * j)) : 0L;
        If0[t] = hi ? 0L : pat;
        If1[t] = hi ? pat : 0L;
    }

    float l0 = 0.0f, l1 = 0.0f, l2 = 0.0f, l3 = 0.0f;

    // ---- double-buffered gather pipeline.
    ulonglong2 An01, An23, Af01, Af23, Am01, Am23;   // set A
    ulonglong2 Bq01, Bq23, Bf01, Bf23, Bm01, Bm23;   // set B

    int inA, imA, ifA, inB = 0, imB = 0, ifB = 0;
    {
        const int s = SIDX(0);
        inA = pos_n[s]; imA = pos_m[s]; ifA = pos_f[s];
    }
    GATHER6(An01, An23, Af01, Af23, Am01, Am23, inA, imA, ifA);
    if (iters > 1) {
        const int s = SIDX(1);
        inB = pos_n[s]; imB = pos_m[s]; ifB = pos_f[s];
    }

#pragma unroll 1
    for (int it = 0; it < iters; it += 2) {
        if (it + 1 < iters)
            GATHER6(Bq01, Bq23, Bf01, Bf23, Bm01, Bm23, inB, imB, ifB);
        if (it + 2 < iters) {
            const int s = SIDX(it + 2);
            inA = pos_n[s]; imA = pos_m[s]; ifA = pos_f[s];
        }
        COMPUTE6(An01, An23, Af01, Af23, Am01, Am23);
        if (it + 2 < iters)
            GATHER6(An01, An23, Af01, Af23, Am01, Am23, inA, imA, ifA);
        if (it + 3 < iters) {
            const int s = SIDX(it + 3);
            inB = pos_n[s]; imB = pos_m[s]; ifB = pos_f[s];
        }
        if (it + 1 < iters)
            COMPUTE6(Bq01, Bq23, Bf01, Bf23, Bm01, Bm23);
    }

    float loss = (l0 + l1) + (l2 + l3);
#pragma unroll
    for (int o = 32; o > 0; o >>= 1) loss += __shfl_xor(loss, o, 64);

    // block-level reduction: 1 atomic per block instead of 4.
    __shared__ float red[4];
    if (lane == 0) red[wave] = loss;
    __syncthreads();
    if (threadIdx.x == 0)
        atomicAdd(out, (red[0] + red[1]) + (red[2] + red[3]));
}

// ---- fallback: fp32 tables with LDS staging (round-4 style), if ws too small.
#define ROW_BYTES 144
__global__ __launch_bounds__(256, 2) void ontomap_kernel_f32(
    const int* __restrict__ pos_n, const int* __restrict__ pos_m,
    const int* __restrict__ pos_f,
    const float* __restrict__ nci, const float* __restrict__ fma_emb,
    const float* __restrict__ n2f, const float* __restrict__ m2f,
    float* __restrict__ out, int iters)
{
    __shared__ char lds[4 * 2 * 32 * ROW_BYTES];

    const int lane = threadIdx.x & 63;
    const int wave = threadIdx.x >> 6;
    const int l31  = lane & 31;
    const int hi   = lane >> 5;
    const int kbase = hi * 8;
    const int srow   = lane >> 4;
    const int schunk = lane & 15;

    char* const nbase = lds + wave * (2 * 32 * ROW_BYTES);
    char* const mbase = nbase + 32 * ROW_BYTES;

    half8 Bn[2][4], Bm[2][4];
#pragma unroll
    for (int nt = 0; nt < 2; ++nt) {
#pragma unroll
        for (int t = 0; t < 4; ++t) {
            const float* p = n2f + (nt * 32 + l31) * 64 + t * 16 + kbase;
            Bn[nt][t] = cvt8(*(const float4*)p, *(const float4*)(p + 4));
            const float* q = m2f + (nt * 32 + l31) * 64 + t * 16 + kbase;
            Bm[nt][t] = cvt8(*(const float4*)q, *(const float4*)(q + 4));
        }
    }

    float loss = 0.0f;
    int in_, im_, if_;
    {
        int s = blockIdx.x * SPB + wave * 32 + l31;
        in_ = pos_n[s]; im_ = pos_m[s]; if_ = pos_f[s];
    }

#pragma unroll 1
    for (int it = 0; it < iters; ++it) {
        const int in0 = in_, im0 = im_, if0 = if_;
        if (it + 1 < iters) {
            int s = ((it + 1) * NBLOCKS + blockIdx.x) * SPB + wave * 32 + l31;
            in_ = pos_n[s]; im_ = pos_m[s]; if_ = pos_f[s];
        }

#pragma unroll
        for (int i = 0; i < 8; ++i) {
            const int rl = i * 4 + srow;
            const int rn = __shfl(in0, rl, 64);
            float4 v = ((const float4*)(nci + (long)rn * 64))[schunk];
            *(uint2*)(nbase + rl * ROW_BYTES + schunk * 8) = pack4(v);
            const int rm = __shfl(im0, rl, 64);
            float4 w = ((const float4*)(nci + (long)rm * 64))[schunk];
            *(uint2*)(mbase + rl * ROW_BYTES + schunk * 8) = pack4(w);
        }
        asm volatile("" ::: "memory");

        floatx16 aN0{}, aN1{}, aM0{}, aM1{};
#pragma unroll
        for (int t = 0; t < 4; ++t) {
            half8 aF = *(const half8*)(nbase + l31 * ROW_BYTES + t * 32 + hi * 16);
            aN0 = __builtin_amdgcn_mfma_f32_32x32x16_f16(aF, Bn[0][t], aN0, 0, 0, 0);
            aN1 = __builtin_amdgcn_mfma_f32_32x32x16_f16(aF, Bn[1][t], aN1, 0, 0, 0);
            half8 bF = *(const half8*)(mbase + l31 * ROW_BYTES + t * 32 + hi * 16);
            aM0 = __builtin_amdgcn_mfma_f32_32x32x16_f16(bF, Bm[0][t], aM0, 0, 0, 0);
            aM1 = __builtin_amdgcn_mfma_f32_32x32x16_f16(bF, Bm[1][t], aM1, 0, 0, 0);
        }

#pragma unroll
        for (int r = 0; r < 16; ++r) {
            const int mrow = (r & 3) + 8 * (r >> 2) + 4 * hi;
            const int fid  = __shfl(if0, mrow, 64);
            const float* pf = fma_emb + (long)fid * 64 + l31;
            const float f0 = pf[0];
            const float f1 = pf[32];
            float d;
            d = aN0[r] - f0; loss = fmaf(d, d, loss);
            d = aM0[r] - f0; loss = fmaf(d, d, loss);
            d = aN1[r] - f1; loss = fmaf(d, d, loss);
            d = aM1[r] - f1; loss = fmaf(d, d, loss);
        }
    }

#pragma unroll
    for (int o = 32; o > 0; o >>= 1) loss += __shfl_xor(loss, o, 64);
    if (lane == 0) atomicAdd(out, loss);
}

extern "C" void kernel_launch(void* const* d_in, const int* in_sizes, int n_in,
                              void* d_out, int out_size, void* d_ws, size_t ws_size,
                              hipStream_t stream) {
    const int*   pos_n   = (const int*)d_in[0];
    const int*   pos_m   = (const int*)d_in[1];
    const int*   pos_f   = (const int*)d_in[2];
    const float* nci_emb = (const float*)d_in[3];
    const float* fma_emb = (const float*)d_in[4];
    const float* n2f_mat = (const float*)d_in[5];
    const float* m2f_mat = (const float*)d_in[6];
    float* out = (float*)d_out;

    const int B = in_sizes[0];
    const int iters = B / (NBLOCKS * SPB);  // 1,048,576 -> 4

    const size_t TBL  = (size_t)NCI_ELEMS + (size_t)FMA_ELEMS;          // 16,000,000
    const size_t need = TBL + (size_t)FRAG_LONGS * sizeof(long);        // +8 KB
    if (ws_size >= need) {
        unsigned char* nci8 = (unsigned char*)d_ws;
        unsigned char* fma8 = nci8 + NCI_ELEMS;   // 9,600,000 is 64B-aligned
        long* fragN = (long*)(nci8 + TBL);        // 16,000,000 is 64B-aligned
        long* fragM = fragN + 8 * 64;
        convert_kernel<<<2048, 256, 0, stream>>>(
            (const float4*)nci_emb, (const float4*)fma_emb,
            (uint4*)nci8, (uint4*)fma8, out, n2f_mat, m2f_mat, fragN, fragM);
        ontomap_kernel_q<<<NBLOCKS, 256, 0, stream>>>(
            pos_n, pos_m, pos_f, nci8, fma8, fragN, fragM, out, iters);
    } else {
        (void)hipMemsetAsync(out, 0, sizeof(float), stream);
        ontomap_kernel_f32<<<NBLOCKS, 256, 0, stream>>>(
            pos_n, pos_m, pos_f, nci_emb, fma_emb, n2f_mat, m2f_mat, out, iters);
    }
}

// Round 10
// 156.290 us; speedup vs baseline: 1.6574x; 1.0152x over previous
//
#include <hip/hip_runtime.h>
#include <hip/hip_fp16.h>

// Ontomap: loss = sum((n2f@n_e - f_e)^2) + sum((m2f@m_e - f_e)^2)
// B = 1,048,576, D = 64.
// Round 20: depth-3 gather pipeline. R16 vs R19 was a confounded A/B:
// R16 = ~10 waves/CU x 6 lines = 60 in flight; R19 = ~5.4 x 12 = 65 --
// same total concurrency, same 53.6us, same 2.95 TB/s. The latency model
// (2.42M L2-miss lines x ~700cy / 53.6us => ~60 lines/CU) fits both.
// iters==4 always (B fixed), so fully unroll: gather(0,1,2) -> compute0 ||
// gather(3) -> compute1..3. 18 lines/wave in flight; even at ~5.4 waves/CU
// that's ~97+ lines/CU (+50-85%). Peak regs ~160 < 256 cap of (256,2):
// no spill expected. Numerics identical (same ops, same order).

typedef _Float16 half8 __attribute__((ext_vector_type(8)));
typedef __fp16  fp16x2 __attribute__((ext_vector_type(2)));
typedef float floatx16 __attribute__((ext_vector_type(16)));

#define NBLOCKS 2048
#define SPB 128                 // samples per block-iteration: 4 waves * 32
#define NCI_ELEMS 9600000       // 150000 * 64
#define FMA_ELEMS 6400000       // 100000 * 64
#define FRAG_LONGS 512          // 2 matrices * 8 frags * 64 lanes

__device__ inline half8 cvt8(float4 a, float4 b) {
    union { half8 h; fp16x2 h2[4]; } u;
    u.h2[0] = __builtin_amdgcn_cvt_pkrtz(a.x, a.y);
    u.h2[1] = __builtin_amdgcn_cvt_pkrtz(a.z, a.w);
    u.h2[2] = __builtin_amdgcn_cvt_pkrtz(b.x, b.y);
    u.h2[3] = __builtin_amdgcn_cvt_pkrtz(b.z, b.w);
    return u.h;
}

__device__ inline uint2 pack4(float4 v) {
    union { fp16x2 h2[2]; uint2 u; } p;
    p.h2[0] = __builtin_amdgcn_cvt_pkrtz(v.x, v.y);
    p.h2[1] = __builtin_amdgcn_cvt_pkrtz(v.z, v.w);
    return p.u;
}

// 8 fp32 -> 8 fp8-e4m3 bytes (ascending order).
__device__ inline uint2 pack8_fp8(float4 a, float4 b) {
    int lo = 0, hi = 0;
    lo = __builtin_amdgcn_cvt_pk_fp8_f32(a.x, a.y, lo, false);
    lo = __builtin_amdgcn_cvt_pk_fp8_f32(a.z, a.w, lo, true);
    hi = __builtin_amdgcn_cvt_pk_fp8_f32(b.x, b.y, hi, false);
    hi = __builtin_amdgcn_cvt_pk_fp8_f32(b.z, b.w, hi, true);
    uint2 r; r.x = (unsigned)lo; r.y = (unsigned)hi; return r;
}

__device__ inline long pack8_fp8_l(const float* p) {
    uint2 b = pack8_fp8(*(const float4*)p, *(const float4*)(p + 4));
    return (long)(((unsigned long)b.y << 32) | b.x);
}

// ---- streaming conversion: both tables -> fp8, into workspace.
// Also zeroes the loss accumulator and precomputes the per-lane packed
// B-fragments for both matrices (frag[(nt*4+t)*64 + lane], 8KB total).
__global__ __launch_bounds__(256) void convert_kernel(
    const float4* __restrict__ nci, const float4* __restrict__ fma,
    uint4* __restrict__ nci8, uint4* __restrict__ fma8, float* __restrict__ out,
    const float* __restrict__ n2f, const float* __restrict__ m2f,
    long* __restrict__ fragN, long* __restrict__ fragM)
{
    const int stride = gridDim.x * blockDim.x;
    const int tid = blockIdx.x * blockDim.x + threadIdx.x;
    if (tid == 0) out[0] = 0.0f;
    if (blockIdx.x == 0 && threadIdx.x < 64) {
        const int lane = threadIdx.x;
        const int l31 = lane & 31;
        const int hoff = (lane >> 5) * 32;
#pragma unroll
        for (int nt = 0; nt < 2; ++nt) {
#pragma unroll
            for (int t = 0; t < 4; ++t) {
                fragN[(nt * 4 + t) * 64 + lane] =
                    pack8_fp8_l(n2f + (nt * 32 + l31) * 64 + hoff + t * 8);
                fragM[(nt * 4 + t) * 64 + lane] =
                    pack8_fp8_l(m2f + (nt * 32 + l31) * 64 + hoff + t * 8);
            }
        }
    }
    for (int i = tid; i < NCI_ELEMS / 16; i += stride) {
        uint2 lo = pack8_fp8(nci[4 * i],     nci[4 * i + 1]);
        uint2 hi = pack8_fp8(nci[4 * i + 2], nci[4 * i + 3]);
        nci8[i] = make_uint4(lo.x, lo.y, hi.x, hi.y);
    }
    for (int i = tid; i < FMA_ELEMS / 16; i += stride) {
        uint2 lo = pack8_fp8(fma[4 * i],     fma[4 * i + 1]);
        uint2 hi = pack8_fp8(fma[4 * i + 2], fma[4 * i + 3]);
        fma8[i] = make_uint4(lo.x, lo.y, hi.x, hi.y);
    }
}

// ---- main kernel: fp8 tables, K-remapped dwordx4 gathers, depth-3
// software pipeline over the (fixed) 4 sample-iterations.

#define GATHER6(n01, n23, f01, f23, m01, m23, in_, im_, if__) do {            \
    const unsigned char* pn_ = nci8 + (long)(in_) * 64 + hoff;                \
    const unsigned char* pf_ = fma8 + (long)(if__) * 64 + hoff;               \
    const unsigned char* pm_ = nci8 + (long)(im_) * 64 + hoff;                \
    n01 = *(const ulonglong2*)pn_;  n23 = *(const ulonglong2*)(pn_ + 16);     \
    f01 = *(const ulonglong2*)pf_;  f23 = *(const ulonglong2*)(pf_ + 16);     \
    m01 = *(const ulonglong2*)pm_;  m23 = *(const ulonglong2*)(pm_ + 16);     \
} while (0)

#define COMPUTE6(n01, n23, f01, f23, m01, m23) do {                           \
    const long An_[4] = {(long)n01.x, (long)n01.y, (long)n23.x, (long)n23.y}; \
    const long Ff_[4] = {(long)f01.x, (long)f01.y, (long)f23.x, (long)f23.y}; \
    const long Am_[4] = {(long)m01.x, (long)m01.y, (long)m23.x, (long)m23.y}; \
    {   floatx16 a{};                                                         \
        _Pragma("unroll")                                                     \
        for (int t = 0; t < 4; ++t)                                           \
            a = __builtin_amdgcn_mfma_f32_32x32x16_fp8_fp8(An_[t], Bn[0][t], a, 0, 0, 0); \
        _Pragma("unroll")                                                     \
        for (int t = 0; t < 4; ++t)                                           \
            a = __builtin_amdgcn_mfma_f32_32x32x16_fp8_fp8(Ff_[t], If0[t], a, 0, 0, 0);   \
        _Pragma("unroll")                                                     \
        for (int r = 0; r < 16; r += 4) {                                     \
            l0 = fmaf(a[r],     a[r],     l0);                                \
            l1 = fmaf(a[r + 1], a[r + 1], l1);                                \
            l2 = fmaf(a[r + 2], a[r + 2], l2);                                \
            l3 = fmaf(a[r + 3], a[r + 3], l3);                                \
        }                                                                     \
    }                                                                         \
    {   floatx16 a{};                                                         \
        _Pragma("unroll")                                                     \
        for (int t = 0; t < 4; ++t)                                           \
            a = __builtin_amdgcn_mfma_f32_32x32x16_fp8_fp8(An_[t], Bn[1][t], a, 0, 0, 0); \
        _Pragma("unroll")                                                     \
        for (int t = 0; t < 4; ++t)                                           \
            a = __builtin_amdgcn_mfma_f32_32x32x16_fp8_fp8(Ff_[t], If1[t], a, 0, 0, 0);   \
        _Pragma("unroll")                                                     \
        for (int r = 0; r < 16; r += 4) {                                     \
            l0 = fmaf(a[r],     a[r],     l0);                                \
            l1 = fmaf(a[r + 1], a[r + 1], l1);                                \
            l2 = fmaf(a[r + 2], a[r + 2], l2);                                \
            l3 = fmaf(a[r + 3], a[r + 3], l3);                                \
        }                                                                     \
    }                                                                         \
    {   floatx16 a{};                                                         \
        _Pragma("unroll")                                                     \
        for (int t = 0; t < 4; ++t)                                           \
            a = __builtin_amdgcn_mfma_f32_32x32x16_fp8_fp8(Am_[t], Bm[0][t], a, 0, 0, 0); \
        _Pragma("unroll")                                                     \
        for (int t = 0; t < 4; ++t)                                           \
            a = __builtin_amdgcn_mfma_f32_32x32x16_fp8_fp8(Ff_[t], If0[t], a, 0, 0, 0);   \
        _Pragma("unroll")                                                     \
        for (int r = 0; r < 16; r += 4) {                                     \
            l0 = fmaf(a[r],     a[r],     l0);                                \
            l1 = fmaf(a[r + 1], a[r + 1], l1);                                \
            l2 = fmaf(a[r + 2], a[r + 2], l2);                                \
            l3 = fmaf(a[r + 3], a[r + 3], l3);                                \
        }                                                                     \
    }                                                                         \
    {   floatx16 a{};                                                         \
        _Pragma("unroll")                                                     \
        for (int t = 0; t < 4; ++t)                                           \
            a = __builtin_amdgcn_mfma_f32_32x32x16_fp8_fp8(Am_[t], Bm[1][t], a, 0, 0, 0); \
        _Pragma("unroll")                                                     \
        for (int t = 0; t < 4; ++t)                                           \
            a = __builtin_amdgcn_mfma_f32_32x32x16_fp8_fp8(Ff_[t], If1[t], a, 0, 0, 0);   \
        _Pragma("unroll")                                                     \
        for (int r = 0; r < 16; r += 4) {                                     \
            l0 = fmaf(a[r],     a[r],     l0);                                \
            l1 = fmaf(a[r + 1], a[r + 1], l1);                                \
            l2 = fmaf(a[r + 2], a[r + 2], l2);                                \
            l3 = fmaf(a[r + 3], a[r + 3], l3);                                \
        }                                                                     \
    }                                                                         \
} while (0)

__global__ __launch_bounds__(256, 2) void ontomap_kernel_q(
    const int* __restrict__ pos_n, const int* __restrict__ pos_m,
    const int* __restrict__ pos_f,
    const unsigned char* __restrict__ nci8, const unsigned char* __restrict__ fma8,
    const long* __restrict__ fragN, const long* __restrict__ fragM,
    float* __restrict__ out)
{
    const int lane = threadIdx.x & 63;
    const int wave = threadIdx.x >> 6;
    const int l31  = lane & 31;
    const int hi   = lane >> 5;
    const int hoff = hi * 32;     // this lane's contiguous 32-byte half-row

    // B fragments (precomputed in convert_kernel): 16 coalesced L2-hit loads.
    long Bn[2][4], Bm[2][4];
#pragma unroll
    for (int nt = 0; nt < 2; ++nt) {
#pragma unroll
        for (int t = 0; t < 4; ++t) {
            Bn[nt][t] = fragN[(nt * 4 + t) * 64 + lane];
            Bm[nt][t] = fragM[(nt * 4 + t) * 64 + lane];
        }
    }

    // -I fragments (fp8 0xB8 = -1.0 e4m3). Step t has -1 at byte j = l31-t*8
    // when 0 <= j < 8; tile0's diagonal in hi=0 slots, tile1's in hi=1.
    long If0[4], If1[4];
#pragma unroll
    for (int t = 0; t < 4; ++t) {
        const unsigned j = (unsigned)(l31 - t * 8);
        const long pat = (j < 8) ? (long)(0xB8ULL << (8 * j)) : 0L;
        If0[t] = hi ? 0L : pat;
        If1[t] = hi ? pat : 0L;
    }

    float l0 = 0.0f, l1 = 0.0f, l2 = 0.0f, l3 = 0.0f;

    // ---- all 4 iterations' indices up front (coalesced).
    const int base = blockIdx.x * SPB + wave * 32 + l31;
    const int D = NBLOCKS * SPB;
    const int n0 = pos_n[base],         m0 = pos_m[base],         f0 = pos_f[base];
    const int n1 = pos_n[base + D],     m1 = pos_m[base + D],     f1 = pos_f[base + D];
    const int n2 = pos_n[base + 2 * D], m2 = pos_m[base + 2 * D], f2 = pos_f[base + 2 * D];
    const int n3 = pos_n[base + 3 * D], m3 = pos_m[base + 3 * D], f3 = pos_f[base + 3 * D];

    // ---- depth-3 pipeline over 4 iterations.
    ulonglong2 a01, a23, af01, af23, am01, am23;   // set 0
    ulonglong2 b01, b23, bf01, bf23, bm01, bm23;   // set 1
    ulonglong2 c01, c23, cf01, cf23, cm01, cm23;   // set 2

    GATHER6(a01, a23, af01, af23, am01, am23, n0, m0, f0);
    GATHER6(b01, b23, bf01, bf23, bm01, bm23, n1, m1, f1);
    GATHER6(c01, c23, cf01, cf23, cm01, cm23, n2, m2, f2);

    COMPUTE6(a01, a23, af01, af23, am01, am23);
    GATHER6(a01, a23, af01, af23, am01, am23, n3, m3, f3);
    COMPUTE6(b01, b23, bf01, bf23, bm01, bm23);
    COMPUTE6(c01, c23, cf01, cf23, cm01, cm23);
    COMPUTE6(a01, a23, af01, af23, am01, am23);

    float loss = (l0 + l1) + (l2 + l3);
#pragma unroll
    for (int o = 32; o > 0; o >>= 1) loss += __shfl_xor(loss, o, 64);

    // block-level reduction: 1 atomic per block instead of 4.
    __shared__ float red[4];
    if (lane == 0) red[wave] = loss;
    __syncthreads();
    if (threadIdx.x == 0)
        atomicAdd(out, (red[0] + red[1]) + (red[2] + red[3]));
}

// ---- fallback: fp32 tables with LDS staging (round-4 style), if ws too small
// or iters != 4.
#define ROW_BYTES 144
__global__ __launch_bounds__(256, 2) void ontomap_kernel_f32(
    const int* __restrict__ pos_n, const int* __restrict__ pos_m,
    const int* __restrict__ pos_f,
    const float* __restrict__ nci, const float* __restrict__ fma_emb,
    const float* __restrict__ n2f, const float* __restrict__ m2f,
    float* __restrict__ out, int iters)
{
    __shared__ char lds[4 * 2 * 32 * ROW_BYTES];

    const int lane = threadIdx.x & 63;
    const int wave = threadIdx.x >> 6;
    const int l31  = lane & 31;
    const int hi   = lane >> 5;
    const int kbase = hi * 8;
    const int srow   = lane >> 4;
    const int schunk = lane & 15;

    char* const nbase = lds + wave * (2 * 32 * ROW_BYTES);
    char* const mbase = nbase + 32 * ROW_BYTES;

    half8 Bn[2][4], Bm[2][4];
#pragma unroll
    for (int nt = 0; nt < 2; ++nt) {
#pragma unroll
        for (int t = 0; t < 4; ++t) {
            const float* p = n2f + (nt * 32 + l31) * 64 + t * 16 + kbase;
            Bn[nt][t] = cvt8(*(const float4*)p, *(const float4*)(p + 4));
            const float* q = m2f + (nt * 32 + l31) * 64 + t * 16 + kbase;
            Bm[nt][t] = cvt8(*(const float4*)q, *(const float4*)(q + 4));
        }
    }

    float loss = 0.0f;
    int in_, im_, if_;
    {
        int s = blockIdx.x * SPB + wave * 32 + l31;
        in_ = pos_n[s]; im_ = pos_m[s]; if_ = pos_f[s];
    }

#pragma unroll 1
    for (int it = 0; it < iters; ++it) {
        const int in0 = in_, im0 = im_, if0 = if_;
        if (it + 1 < iters) {
            int s = ((it + 1) * NBLOCKS + blockIdx.x) * SPB + wave * 32 + l31;
            in_ = pos_n[s]; im_ = pos_m[s]; if_ = pos_f[s];
        }

#pragma unroll
        for (int i = 0; i < 8; ++i) {
            const int rl = i * 4 + srow;
            const int rn = __shfl(in0, rl, 64);
            float4 v = ((const float4*)(nci + (long)rn * 64))[schunk];
            *(uint2*)(nbase + rl * ROW_BYTES + schunk * 8) = pack4(v);
            const int rm = __shfl(im0, rl, 64);
            float4 w = ((const float4*)(nci + (long)rm * 64))[schunk];
            *(uint2*)(mbase + rl * ROW_BYTES + schunk * 8) = pack4(w);
        }
        asm volatile("" ::: "memory");

        floatx16 aN0{}, aN1{}, aM0{}, aM1{};
#pragma unroll
        for (int t = 0; t < 4; ++t) {
            half8 aF = *(const half8*)(nbase + l31 * ROW_BYTES + t * 32 + hi * 16);
            aN0 = __builtin_amdgcn_mfma_f32_32x32x16_f16(aF, Bn[0][t], aN0, 0, 0, 0);
            aN1 = __builtin_amdgcn_mfma_f32_32x32x16_f16(aF, Bn[1][t], aN1, 0, 0, 0);
            half8 bF = *(const half8*)(mbase + l31 * ROW_BYTES + t * 32 + hi * 16);
            aM0 = __builtin_amdgcn_mfma_f32_32x32x16_f16(bF, Bm[0][t], aM0, 0, 0, 0);
            aM1 = __builtin_amdgcn_mfma_f32_32x32x16_f16(bF, Bm[1][t], aM1, 0, 0, 0);
        }

#pragma unroll
        for (int r = 0; r < 16; ++r) {
            const int mrow = (r & 3) + 8 * (r >> 2) + 4 * hi;
            const int fid  = __shfl(if0, mrow, 64);
            const float* pf = fma_emb + (long)fid * 64 + l31;
            const float f0 = pf[0];
            const float f1 = pf[32];
            float d;
            d = aN0[r] - f0; loss = fmaf(d, d, loss);
            d = aM0[r] - f0; loss = fmaf(d, d, loss);
            d = aN1[r] - f1; loss = fmaf(d, d, loss);
            d = aM1[r] - f1; loss = fmaf(d, d, loss);
        }
    }

#pragma unroll
    for (int o = 32; o > 0; o >>= 1) loss += __shfl_xor(loss, o, 64);
    if (lane == 0) atomicAdd(out, loss);
}

extern "C" void kernel_launch(void* const* d_in, const int* in_sizes, int n_in,
                              void* d_out, int out_size, void* d_ws, size_t ws_size,
                              hipStream_t stream) {
    const int*   pos_n   = (const int*)d_in[0];
    const int*   pos_m   = (const int*)d_in[1];
    const int*   pos_f   = (const int*)d_in[2];
    const float* nci_emb = (const float*)d_in[3];
    const float* fma_emb = (const float*)d_in[4];
    const float* n2f_mat = (const float*)d_in[5];
    const float* m2f_mat = (const float*)d_in[6];
    float* out = (float*)d_out;

    const int B = in_sizes[0];
    const int iters = B / (NBLOCKS * SPB);  // 1,048,576 -> 4

    const size_t TBL  = (size_t)NCI_ELEMS + (size_t)FMA_ELEMS;          // 16,000,000
    const size_t need = TBL + (size_t)FRAG_LONGS * sizeof(long);        // +8 KB
    if (ws_size >= need && iters == 4 && iters * NBLOCKS * SPB == B) {
        unsigned char* nci8 = (unsigned char*)d_ws;
        unsigned char* fma8 = nci8 + NCI_ELEMS;   // 9,600,000 is 64B-aligned
        long* fragN = (long*)(nci8 + TBL);        // 16,000,000 is 64B-aligned
        long* fragM = fragN + 8 * 64;
        convert_kernel<<<2048, 256, 0, stream>>>(
            (const float4*)nci_emb, (const float4*)fma_emb,
            (uint4*)nci8, (uint4*)fma8, out, n2f_mat, m2f_mat, fragN, fragM);
        ontomap_kernel_q<<<NBLOCKS, 256, 0, stream>>>(
            pos_n, pos_m, pos_f, nci8, fma8, fragN, fragM, out);
    } else {
        (void)hipMemsetAsync(out, 0, sizeof(float), stream);
        ontomap_kernel_f32<<<NBLOCKS, 256, 0, stream>>>(
            pos_n, pos_m, pos_f, nci_emb, fma_emb, n2f_mat, m2f_mat, out, iters);
    }
}